// Round 10
// baseline (285.079 us; speedup 1.0000x reference)
//
#include <hip/hip_runtime.h>
#include <hip/hip_bf16.h>

#define HH 256   // hidden dim
#define HJ 128   // H/2
#define GG 512   // number of graphs

typedef __attribute__((ext_vector_type(8))) short short8;
typedef __attribute__((ext_vector_type(4))) float f32x4;

static __device__ __forceinline__ unsigned f2bfu(float f) {
  // round-to-nearest-even fp32 -> bf16 (inputs finite), as low 16 bits
  unsigned u = __builtin_bit_cast(unsigned, f);
  return (u + 0x7FFFu + ((u >> 16) & 1u)) >> 16;
}

// ---------------- Kernel 0: pre-fragment W1^T into MFMA A-operand order ----
// w1a[kt*8+jt][lane] = 8 bf16: A[m=j][k] with j = jt*16+(l&15), k = kt*32+(l>>4)*8+i
__global__ __launch_bounds__(64) void w1frag_kernel(
    const float* __restrict__ W1, short8* __restrict__ w1a) {
  const int l = threadIdx.x;
  const int kt = blockIdx.x >> 3;
  const int jt = blockIdx.x & 7;
  const int j = jt * 16 + (l & 15);
  const int kb = kt * 32 + (l >> 4) * 8;
  short8 v;
#pragma unroll
  for (int i = 0; i < 8; ++i) v[i] = (short)f2bfu(W1[(size_t)(kb + i) * HJ + j]);
  w1a[blockIdx.x * 64 + l] = v;
}

// ---------------- segment offsets from sorted batch ----------------
__global__ __launch_bounds__(256) void segstart_kernel(
    const int* __restrict__ batch, int* __restrict__ segstart, int N, int G) {
  const int n = blockIdx.x * 256 + threadIdx.x;
  if (n >= N) return;
  const int b = batch[n];
  const int p = (n == 0) ? -1 : batch[n - 1];
  for (int g = p + 1; g <= b; ++g) segstart[g] = n;
  if (n == N - 1) {
    for (int g = b + 1; g <= G; ++g) segstart[g] = N;
  }
}

// ---------------- Fused kernel: one block per graph ------------------------
// x rows load COALESCED (1KB bursts, lane=16B) -> bf16 swizzled LDS tile that
// serves BOTH the MFMA B-fragments and the channel-major pool sweep.
// Wave w owns j-tile w: A-frags (W1) in registers. e=exp(s), b2 dropped.
__global__ __launch_bounds__(512, 4) void fused_kernel(
    const float* __restrict__ x, const short8* __restrict__ w1a,
    const float* __restrict__ b1, const float* __restrict__ W2,
    const int* __restrict__ segstart, const float* __restrict__ Wp,
    const float* __restrict__ bp, float4* __restrict__ out4, int N) {
  __shared__ short8 xlds8[4096];    // 64 KB bf16 x-tile [128][256], swizzled
  __shared__ float spart[8 * 128];  // 4 KB; reused as qredf post-loop
  __shared__ float elds[128];
  __shared__ float esl[128];

  const int tid = threadIdx.x;
  const int l = tid & 63;
  const int w = tid >> 6;  // wave 0..7 = j-tile
  const int g = blockIdx.x;

  const int n0 = segstart[g];
  const int n1 = segstart[g + 1];
  const int cnt = n1 - n0;
  if (cnt <= 0) return;  // block-uniform, before any barrier

  const int ntiles = (cnt + 127) >> 7;
  const float4* x4 = (const float4*)x;

  // A-fragments for this wave's j-tile (jt = w): registers, once per block
  short8 afrag[8];
#pragma unroll
  for (int kt = 0; kt < 8; ++kt) afrag[kt] = w1a[(kt * 8 + w) * 64 + l];

  // per-lane b1/W2 for j = 16*w + (l>>4)*4 + r
  const int j0 = 16 * w + (l >> 4) * 4;
  const float4 bb = *reinterpret_cast<const float4*>(b1 + j0);
  const float4 ww = *reinterpret_cast<const float4*>(W2 + j0);

  // sweep mapping
  const int c2 = tid & 127;
  const int qh = tid >> 7;
  float2 pacc = make_float2(0.f, 0.f);
  float es_acc = 0.f;  // valid for tid<128

  char* xl = (char*)xlds8;

  // cur: this tile's 16 rows, 4 bf16 (=8B) per lane per row
  uint2 cur[16];
  float4 fla[8], flb[8];

  // prologue: load + cvt tile 0
#pragma unroll
  for (int i = 0; i < 8; ++i) {
    const int node = n0 + w * 16 + i;
    fla[i] = x4[(size_t)min(node, N - 1) * 64 + l];
  }
#pragma unroll
  for (int i = 0; i < 8; ++i) {
    const int node = n0 + w * 16 + 8 + i;
    flb[i] = x4[(size_t)min(node, N - 1) * 64 + l];
  }
#pragma unroll
  for (int i = 0; i < 8; ++i) {
    const bool v = (n0 + w * 16 + i) < n1;
    cur[i] = v ? make_uint2(f2bfu(fla[i].x) | (f2bfu(fla[i].y) << 16),
                            f2bfu(fla[i].z) | (f2bfu(fla[i].w) << 16))
               : make_uint2(0u, 0u);
    const bool v2 = (n0 + w * 16 + 8 + i) < n1;
    cur[8 + i] = v2 ? make_uint2(f2bfu(flb[i].x) | (f2bfu(flb[i].y) << 16),
                                 f2bfu(flb[i].z) | (f2bfu(flb[i].w) << 16))
                    : make_uint2(0u, 0u);
  }

  for (int t = 0; t < ntiles; ++t) {
    const bool more = (t + 1) < ntiles;
    // ---- write tile t: row r, lane's 4 channels at byte (l*8) ^ swz(r) ----
#pragma unroll
    for (int i = 0; i < 16; ++i) {
      const int r = w * 16 + i;
      *reinterpret_cast<uint2*>(xl + r * 512 + ((l * 8) ^ ((r & 7) << 4))) =
          cur[i];
    }
    __syncthreads();  // B1: tile visible

    // issue next tile's rows 0..7 (hides under MFMA phase)
    if (more) {
#pragma unroll
      for (int i = 0; i < 8; ++i) {
        const int node = n0 + (t + 1) * 128 + w * 16 + i;
        fla[i] = x4[(size_t)min(node, N - 1) * 64 + l];
      }
      __builtin_amdgcn_sched_barrier(0);
    }

    // ---- gate GEMM: wave w computes h[16w..16w+16][all 128 nodes] --------
#pragma unroll
    for (int nt = 0; nt < 8; ++nt) {
      const int ntw = (nt + w) & 7;  // decorrelate waves' LDS banks
      const int node = ntw * 16 + (l & 15);
      const int nb = node * 512;
      const int swz = (node & 7) << 4;
      short8 bfrag[8];
#pragma unroll
      for (int kt = 0; kt < 8; ++kt) {
        bfrag[kt] = *reinterpret_cast<const short8*>(
            xl + nb + ((kt * 64 + ((l >> 4) << 4)) ^ swz));
      }
      f32x4 acc = (f32x4)(0.f);
#pragma unroll
      for (int kt = 0; kt < 8; ++kt) {
        acc = __builtin_amdgcn_mfma_f32_16x16x32_bf16(afrag[kt], bfrag[kt],
                                                      acc, 0, 0, 0);
      }
      // epilogue: partial s over this wave's 16 j's for this node
      float t0 = __expf(2.f * (acc[0] + bb.x));
      float t1 = __expf(2.f * (acc[1] + bb.y));
      float t2 = __expf(2.f * (acc[2] + bb.z));
      float t3 = __expf(2.f * (acc[3] + bb.w));
      float ps = (1.f - 2.f / (t0 + 1.f)) * ww.x +
                 (1.f - 2.f / (t1 + 1.f)) * ww.y +
                 (1.f - 2.f / (t2 + 1.f)) * ww.z +
                 (1.f - 2.f / (t3 + 1.f)) * ww.w;
      ps += __shfl_xor(ps, 16, 64);
      ps += __shfl_xor(ps, 32, 64);
      if (l < 16) spart[w * 128 + ntw * 16 + l] = ps;
    }
    __syncthreads();  // B2: spart ready

    // cvt rows 0..7 (loads have had the whole MFMA phase to land)
    if (more) {
#pragma unroll
      for (int i = 0; i < 8; ++i) {
        const bool v = (n0 + (t + 1) * 128 + w * 16 + i) < n1;
        cur[i] = v ? make_uint2(f2bfu(fla[i].x) | (f2bfu(fla[i].y) << 16),
                                f2bfu(fla[i].z) | (f2bfu(fla[i].w) << 16))
                   : make_uint2(0u, 0u);
      }
    }

    // combine j-slices -> s -> e (one thread per node)
    if (tid < 128) {
      float s = 0.f;
#pragma unroll
      for (int wv = 0; wv < 8; ++wv) s += spart[wv * 128 + tid];
      const int node = n0 + t * 128 + tid;
      const float e = (node < n1) ? __expf(s) : 0.f;
      elds[tid] = e;
      es_acc += e;
    }
    __syncthreads();  // B3: elds ready

    // issue next tile's rows 8..15 (hides under sweep)
    if (more) {
#pragma unroll
      for (int i = 0; i < 8; ++i) {
        const int node = n0 + (t + 1) * 128 + w * 16 + 8 + i;
        flb[i] = x4[(size_t)min(node, N - 1) * 64 + l];
      }
      __builtin_amdgcn_sched_barrier(0);
    }

    // ---- channel-major pool sweep: channels {2c2,2c2+1}, nodes qh*32.. ----
#pragma unroll 8
    for (int m = 0; m < 32; ++m) {
      const int n = qh * 32 + m;
      const unsigned v = *reinterpret_cast<const unsigned*>(
          xl + n * 512 + ((c2 * 4) ^ ((n & 7) << 4)));
      const float ee = elds[n];
      const float xlo = __builtin_bit_cast(float, v << 16);
      const float xhi = __builtin_bit_cast(float, v & 0xFFFF0000u);
      pacc.x = fmaf(xlo, ee, pacc.x);
      pacc.y = fmaf(xhi, ee, pacc.y);
    }

    // cvt rows 8..15
    if (more) {
#pragma unroll
      for (int i = 0; i < 8; ++i) {
        const bool v = (n0 + (t + 1) * 128 + w * 16 + 8 + i) < n1;
        cur[8 + i] = v ? make_uint2(f2bfu(flb[i].x) | (f2bfu(flb[i].y) << 16),
                                    f2bfu(flb[i].z) | (f2bfu(flb[i].w) << 16))
                       : make_uint2(0u, 0u);
      }
    }
    __syncthreads();  // B4: sweep done; tile may be overwritten
  }

  // ---- combine quarter partials; spart reused as qredf [4][256] ----
  float* qredf = spart;
  qredf[qh * 256 + c2 * 2] = pacc.x;
  qredf[qh * 256 + c2 * 2 + 1] = pacc.y;
  if (tid < 128) esl[tid] = es_acc;
  __syncthreads();
  if (tid < 64) esl[tid] += esl[tid + 64];
  __syncthreads();

  float* er = (float*)xlds8;  // x-tile dead: reuse for emb/proj buffers
  if (tid < HH) {
    float es = 0.f;
#pragma unroll 8
    for (int i = 0; i < 64; ++i) es += esl[i];
    const float inv = (es > 0.f) ? 1.f / es : 0.f;
    const float emb =
        qredf[tid] + qredf[256 + tid] + qredf[512 + tid] + qredf[768 + tid];
    er[tid] = emb * inv;
  }
  __syncthreads();

  // projection: ctx = er @ Wp + bp, split over k-halves
  float* pr = er + 256;  // [2][256]
  {
    const int c = tid & 255;
    const int h = tid >> 8;
    float p = 0.f;
    const float* wp = Wp + (size_t)h * 128 * HH + c;
#pragma unroll 4
    for (int k = 0; k < 128; ++k) {
      p = fmaf(er[h * 128 + k], wp[(size_t)k * HH], p);
    }
    pr[h * 256 + c] = p;
  }
  __syncthreads();
  float* ctxl = pr + 512;
  if (tid < HH) {
    ctxl[tid] = pr[tid] + pr[256 + tid] + bp[tid];
  }
  __syncthreads();

  // broadcast ctx row to all nodes of the graph (coalesced 1KB/wave rows)
  {
    const int q = tid & 63;
    const float4 cv = reinterpret_cast<const float4*>(ctxl)[q];
    for (int n = n0 + w; n < n1; n += 8) {
      out4[(size_t)n * 64 + q] = cv;
    }
  }
}

extern "C" void kernel_launch(void* const* d_in, const int* in_sizes, int n_in,
                              void* d_out, int out_size, void* d_ws, size_t ws_size,
                              hipStream_t stream) {
  const float* x = (const float*)d_in[0];
  const int* batch = (const int*)d_in[1];
  const float* W1 = (const float*)d_in[2];
  const float* b1 = (const float*)d_in[3];
  const float* W2 = (const float*)d_in[4];
  // d_in[5] = b2 (unused: softmax shift-invariant)
  const float* Wp = (const float*)d_in[6];
  const float* bp = (const float*)d_in[7];
  float* out = (float*)d_out;

  const int N = in_sizes[1];
  const int G = GG;

  // workspace layout (16B aligned)
  char* wsp = (char*)d_ws;
  short8* w1a = (short8*)wsp;           // 4096 short8 = 64 KB
  size_t off = 4096 * sizeof(short8);
  int* segstart = (int*)(wsp + off);    // G+1 ints

  // fragment W1
  w1frag_kernel<<<dim3(64), 64, 0, stream>>>(W1, w1a);
  // segment offsets
  {
    dim3 grid((N + 255) / 256);
    segstart_kernel<<<grid, 256, 0, stream>>>(batch, segstart, N, G);
  }
  // fused gate + pool + project + broadcast
  fused_kernel<<<dim3(G), 512, 0, stream>>>(x, w1a, b1, W2, segstart, Wp, bp,
                                            (float4*)out, N);
}

// Round 11
// 129.079 us; speedup vs baseline: 2.2086x; 2.2086x over previous
//
#include <hip/hip_runtime.h>
#include <hip/hip_bf16.h>

#define HH 256   // hidden dim
#define HJ 128   // H/2
#define GG 512   // number of graphs

typedef __attribute__((ext_vector_type(8))) short short8;
typedef __attribute__((ext_vector_type(4))) float f32x4;

static __device__ __forceinline__ unsigned f2bfu(float f) {
  // round-to-nearest-even fp32 -> bf16 (inputs finite), as low 16 bits
  unsigned u = __builtin_bit_cast(unsigned, f);
  return (u + 0x7FFFu + ((u >> 16) & 1u)) >> 16;
}

// ---------------- Kernel 0: pre-fragment W1^T into MFMA A-operand order ----
// w1a[kt*8+jt][lane] = 8 bf16: A[m=j][k] with j = jt*16+(l&15), k = kt*32+(l>>4)*8+i
__global__ __launch_bounds__(64) void w1frag_kernel(
    const float* __restrict__ W1, short8* __restrict__ w1a) {
  const int l = threadIdx.x;
  const int kt = blockIdx.x >> 3;
  const int jt = blockIdx.x & 7;
  const int j = jt * 16 + (l & 15);
  const int kb = kt * 32 + (l >> 4) * 8;
  short8 v;
#pragma unroll
  for (int i = 0; i < 8; ++i) v[i] = (short)f2bfu(W1[(size_t)(kb + i) * HJ + j]);
  w1a[blockIdx.x * 64 + l] = v;
}

// ---------------- segment offsets from sorted batch ----------------
__global__ __launch_bounds__(256) void segstart_kernel(
    const int* __restrict__ batch, int* __restrict__ segstart, int N, int G) {
  const int n = blockIdx.x * 256 + threadIdx.x;
  if (n >= N) return;
  const int b = batch[n];
  const int p = (n == 0) ? -1 : batch[n - 1];
  for (int g = p + 1; g <= b; ++g) segstart[g] = n;
  if (n == N - 1) {
    for (int g = b + 1; g <= G; ++g) segstart[g] = N;
  }
}

// ---------------- Fused kernel: one block per graph ------------------------
// Wave w owns j-tile jt=w (A-frags in registers). x rows -> regs (prefetched
// a full phase early) -> swizzled bf16 LDS tile serving both MFMA B-frags and
// the channel-major pool sweep. e=exp(s), b2 dropped (shift-invariant).
__global__ __launch_bounds__(512, 2) void fused_kernel(
    const float* __restrict__ x, const short8* __restrict__ w1a,
    const float* __restrict__ b1, const float* __restrict__ W2,
    const int* __restrict__ segstart, const float* __restrict__ Wp,
    const float* __restrict__ bp, float4* __restrict__ out4, int N) {
  __shared__ short8 xlds8[4096];    // 64 KB bf16 x-tile [128][256], swizzled
  __shared__ float spart[8 * 128];  // 4 KB; reused as qredf post-loop
  __shared__ float elds[128];
  __shared__ float esl[128];

  const int tid = threadIdx.x;
  const int l = tid & 63;
  const int w = tid >> 6;  // wave 0..7 = j-tile
  const int g = blockIdx.x;

  const int n0 = segstart[g];
  const int n1 = segstart[g + 1];
  const int cnt = n1 - n0;
  if (cnt <= 0) return;  // block-uniform, before any barrier

  const int ntiles = (cnt + 127) >> 7;
  const float4* x4 = (const float4*)x;

  // A-fragments for this wave's j-tile (jt = w): registers, once per block
  short8 afrag[8];
#pragma unroll
  for (int kt = 0; kt < 8; ++kt) afrag[kt] = w1a[(kt * 8 + w) * 64 + l];

  // per-lane b1/W2 for j = 16*w + (l>>4)*4 + r
  const int j0 = 16 * w + (l >> 4) * 4;
  const float4 bb = *reinterpret_cast<const float4*>(b1 + j0);
  const float4 ww = *reinterpret_cast<const float4*>(W2 + j0);

  const int lanecol = l & 31;  // float4 index within a half-row
  const int rhalf = l >> 5;    // 0/1: which row of the pair

  // sweep mapping
  const int c2 = tid & 127;
  const int qh = tid >> 7;
  float2 pacc = make_float2(0.f, 0.f);
  float es_acc = 0.f;  // valid for tid<128

  char* xl = (char*)xlds8;
  float4 rrA[8], rrB[8];

  // prologue: load + write tile 0 (rows beyond n1 read clamped real data;
  // their contributions are killed later by e=0)
#pragma unroll
  for (int i = 0; i < 8; ++i) {
    const int node = min(n0 + w * 16 + 2 * i + rhalf, N - 1);
    rrA[i] = x4[(size_t)node * 64 + lanecol];
    rrB[i] = x4[(size_t)node * 64 + 32 + lanecol];
  }
#pragma unroll
  for (int i = 0; i < 8; ++i) {
    const int r = w * 16 + 2 * i + rhalf;
    const int swz = (r & 7) << 4;
    *reinterpret_cast<uint2*>(xl + r * 512 + ((lanecol * 8) ^ swz)) =
        make_uint2(f2bfu(rrA[i].x) | (f2bfu(rrA[i].y) << 16),
                   f2bfu(rrA[i].z) | (f2bfu(rrA[i].w) << 16));
    *reinterpret_cast<uint2*>(xl + r * 512 + ((256 + lanecol * 8) ^ swz)) =
        make_uint2(f2bfu(rrB[i].x) | (f2bfu(rrB[i].y) << 16),
                   f2bfu(rrB[i].z) | (f2bfu(rrB[i].w) << 16));
  }
  __syncthreads();  // B1: tile 0 visible

  for (int t = 0; t < ntiles; ++t) {
    const bool more = (t + 1) < ntiles;

    // issue next tile's first channel-half (hides under MFMA phase)
    if (more) {
#pragma unroll
      for (int i = 0; i < 8; ++i) {
        const int node =
            min(n0 + (t + 1) * 128 + w * 16 + 2 * i + rhalf, N - 1);
        rrA[i] = x4[(size_t)node * 64 + lanecol];
      }
      __builtin_amdgcn_sched_barrier(0);
    }

    // ---- gate GEMM: wave w computes h[16w..16w+16][all 128 nodes] --------
#pragma unroll
    for (int nt = 0; nt < 8; ++nt) {
      const int ntw = (nt + w) & 7;  // decorrelate waves' LDS banks
      const int node = ntw * 16 + (l & 15);
      const int nb = node * 512;
      const int swz = (node & 7) << 4;
      f32x4 acc = (f32x4)(0.f);
#pragma unroll
      for (int kh = 0; kh < 2; ++kh) {
        short8 bfrag[4];
#pragma unroll
        for (int kk = 0; kk < 4; ++kk) {
          const int kt = kh * 4 + kk;
          bfrag[kk] = *reinterpret_cast<const short8*>(
              xl + nb + ((kt * 64 + ((l >> 4) << 4)) ^ swz));
        }
#pragma unroll
        for (int kk = 0; kk < 4; ++kk) {
          acc = __builtin_amdgcn_mfma_f32_16x16x32_bf16(afrag[kh * 4 + kk],
                                                        bfrag[kk], acc, 0, 0, 0);
        }
      }
      // epilogue: partial s over this wave's 16 j's for this node
      float t0 = __expf(2.f * (acc[0] + bb.x));
      float t1 = __expf(2.f * (acc[1] + bb.y));
      float t2 = __expf(2.f * (acc[2] + bb.z));
      float t3 = __expf(2.f * (acc[3] + bb.w));
      float ps = (1.f - 2.f / (t0 + 1.f)) * ww.x +
                 (1.f - 2.f / (t1 + 1.f)) * ww.y +
                 (1.f - 2.f / (t2 + 1.f)) * ww.z +
                 (1.f - 2.f / (t3 + 1.f)) * ww.w;
      ps += __shfl_xor(ps, 16, 64);
      ps += __shfl_xor(ps, 32, 64);
      if (l < 16) spart[w * 128 + ntw * 16 + l] = ps;
    }
    __syncthreads();  // B2: spart ready

    // combine j-slices -> s -> e (one thread per node)
    if (tid < 128) {
      float s = 0.f;
#pragma unroll
      for (int wv = 0; wv < 8; ++wv) s += spart[wv * 128 + tid];
      const int node = n0 + t * 128 + tid;
      const float e = (node < n1) ? __expf(s) : 0.f;
      elds[tid] = e;
      es_acc += e;
    }
    __syncthreads();  // B3: elds ready

    // issue next tile's second channel-half (hides under sweep)
    if (more) {
#pragma unroll
      for (int i = 0; i < 8; ++i) {
        const int node =
            min(n0 + (t + 1) * 128 + w * 16 + 2 * i + rhalf, N - 1);
        rrB[i] = x4[(size_t)node * 64 + 32 + lanecol];
      }
      __builtin_amdgcn_sched_barrier(0);
    }

    // ---- channel-major pool sweep: channels {2c2,2c2+1}, nodes qh*32.. ----
#pragma unroll 8
    for (int m = 0; m < 32; ++m) {
      const int n = qh * 32 + m;
      const unsigned v = *reinterpret_cast<const unsigned*>(
          xl + n * 512 + ((c2 * 4) ^ ((n & 7) << 4)));
      const float ee = elds[n];
      const float xlo = __builtin_bit_cast(float, v << 16);
      const float xhi = __builtin_bit_cast(float, v & 0xFFFF0000u);
      pacc.x = fmaf(xlo, ee, pacc.x);
      pacc.y = fmaf(xhi, ee, pacc.y);
    }
    __syncthreads();  // B4: all reads of tile t done

    // write tile t+1 from prefetch regs (bf16, XOR-swizzled)
    if (more) {
#pragma unroll
      for (int i = 0; i < 8; ++i) {
        const int r = w * 16 + 2 * i + rhalf;
        const int swz = (r & 7) << 4;
        *reinterpret_cast<uint2*>(xl + r * 512 + ((lanecol * 8) ^ swz)) =
            make_uint2(f2bfu(rrA[i].x) | (f2bfu(rrA[i].y) << 16),
                       f2bfu(rrA[i].z) | (f2bfu(rrA[i].w) << 16));
        *reinterpret_cast<uint2*>(xl + r * 512 + ((256 + lanecol * 8) ^ swz)) =
            make_uint2(f2bfu(rrB[i].x) | (f2bfu(rrB[i].y) << 16),
                       f2bfu(rrB[i].z) | (f2bfu(rrB[i].w) << 16));
      }
      __syncthreads();  // B1': tile t+1 visible
    }
  }

  // ---- combine quarter partials; spart reused as qredf [4][256] ----
  float* qredf = spart;
  qredf[qh * 256 + c2 * 2] = pacc.x;
  qredf[qh * 256 + c2 * 2 + 1] = pacc.y;
  if (tid < 128) esl[tid] = es_acc;
  __syncthreads();
  if (tid < 64) esl[tid] += esl[tid + 64];
  __syncthreads();

  float* er = (float*)xlds8;  // x-tile dead: reuse for emb/proj buffers
  if (tid < HH) {
    float es = 0.f;
#pragma unroll 8
    for (int i = 0; i < 64; ++i) es += esl[i];
    const float inv = (es > 0.f) ? 1.f / es : 0.f;
    const float emb =
        qredf[tid] + qredf[256 + tid] + qredf[512 + tid] + qredf[768 + tid];
    er[tid] = emb * inv;
  }
  __syncthreads();

  // projection: ctx = er @ Wp + bp, split over k-halves
  float* pr = er + 256;  // [2][256]
  {
    const int c = tid & 255;
    const int h = tid >> 8;
    float p = 0.f;
    const float* wp = Wp + (size_t)h * 128 * HH + c;
#pragma unroll 4
    for (int k = 0; k < 128; ++k) {
      p = fmaf(er[h * 128 + k], wp[(size_t)k * HH], p);
    }
    pr[h * 256 + c] = p;
  }
  __syncthreads();
  float* ctxl = pr + 512;
  if (tid < HH) {
    ctxl[tid] = pr[tid] + pr[256 + tid] + bp[tid];
  }
  __syncthreads();

  // broadcast ctx row to all nodes of the graph (coalesced 1KB/wave rows)
  {
    const int q = tid & 63;
    const float4 cv = reinterpret_cast<const float4*>(ctxl)[q];
    for (int n = n0 + w; n < n1; n += 8) {
      out4[(size_t)n * 64 + q] = cv;
    }
  }
}

extern "C" void kernel_launch(void* const* d_in, const int* in_sizes, int n_in,
                              void* d_out, int out_size, void* d_ws, size_t ws_size,
                              hipStream_t stream) {
  const float* x = (const float*)d_in[0];
  const int* batch = (const int*)d_in[1];
  const float* W1 = (const float*)d_in[2];
  const float* b1 = (const float*)d_in[3];
  const float* W2 = (const float*)d_in[4];
  // d_in[5] = b2 (unused: softmax shift-invariant)
  const float* Wp = (const float*)d_in[6];
  const float* bp = (const float*)d_in[7];
  float* out = (float*)d_out;

  const int N = in_sizes[1];
  const int G = GG;

  // workspace layout (16B aligned)
  char* wsp = (char*)d_ws;
  short8* w1a = (short8*)wsp;           // 4096 short8 = 64 KB
  size_t off = 4096 * sizeof(short8);
  int* segstart = (int*)(wsp + off);    // G+1 ints

  // fragment W1
  w1frag_kernel<<<dim3(64), 64, 0, stream>>>(W1, w1a);
  // segment offsets
  {
    dim3 grid((N + 255) / 256);
    segstart_kernel<<<grid, 256, 0, stream>>>(batch, segstart, N, G);
  }
  // fused gate + pool + project + broadcast
  fused_kernel<<<dim3(G), 512, 0, stream>>>(x, w1a, b1, W2, segstart, Wp, bp,
                                            (float4*)out, N);
}

// Round 12
// 126.894 us; speedup vs baseline: 2.2466x; 1.0172x over previous
//
#include <hip/hip_runtime.h>
#include <hip/hip_bf16.h>

#define HH 256   // hidden dim
#define HJ 128   // H/2
#define GG 512   // number of graphs

typedef __attribute__((ext_vector_type(8))) short short8;
typedef __attribute__((ext_vector_type(4))) float f32x4;

static __device__ __forceinline__ unsigned f2bfu(float f) {
  // round-to-nearest-even fp32 -> bf16 (inputs finite), as low 16 bits
  unsigned u = __builtin_bit_cast(unsigned, f);
  return (u + 0x7FFFu + ((u >> 16) & 1u)) >> 16;
}

static __device__ __forceinline__ uint2 pack4(const float4 f) {
  return make_uint2(f2bfu(f.x) | (f2bfu(f.y) << 16),
                    f2bfu(f.z) | (f2bfu(f.w) << 16));
}

// ---------------- Kernel 0: pre-fragment W1^T into MFMA A-operand order ----
// w1a[kt*8+jt][lane] = 8 bf16: A[m=j][k] with j = jt*16+(l&15), k = kt*32+(l>>4)*8+i
__global__ __launch_bounds__(64) void w1frag_kernel(
    const float* __restrict__ W1, short8* __restrict__ w1a) {
  const int l = threadIdx.x;
  const int kt = blockIdx.x >> 3;
  const int jt = blockIdx.x & 7;
  const int j = jt * 16 + (l & 15);
  const int kb = kt * 32 + (l >> 4) * 8;
  short8 v;
#pragma unroll
  for (int i = 0; i < 8; ++i) v[i] = (short)f2bfu(W1[(size_t)(kb + i) * HJ + j]);
  w1a[blockIdx.x * 64 + l] = v;
}

// ---------------- segment offsets from sorted batch ----------------
__global__ __launch_bounds__(256) void segstart_kernel(
    const int* __restrict__ batch, int* __restrict__ segstart, int N, int G) {
  const int n = blockIdx.x * 256 + threadIdx.x;
  if (n >= N) return;
  const int b = batch[n];
  const int p = (n == 0) ? -1 : batch[n - 1];
  for (int g = p + 1; g <= b; ++g) segstart[g] = n;
  if (n == N - 1) {
    for (int g = b + 1; g <= G; ++g) segstart[g] = N;
  }
}

// ---------------- Fused kernel: one block per graph ------------------------
// Wave w owns j-tile jt=w (A-frags in registers). x rows -> regs (prefetched
// a full phase early; first half packed to bf16 mid-pipeline to cut VGPR) ->
// swizzled bf16 LDS tile serving both MFMA B-frags and the pool sweep.
__global__ __launch_bounds__(512, 2) void fused_kernel(
    const float* __restrict__ x, const short8* __restrict__ w1a,
    const float* __restrict__ b1, const float* __restrict__ W2,
    const int* __restrict__ segstart, const float* __restrict__ Wp,
    const float* __restrict__ bp, float4* __restrict__ out4, int N) {
  __shared__ short8 xlds8[4096];    // 64 KB bf16 x-tile [128][256], swizzled
  __shared__ float spart[8 * 128];  // 4 KB; reused as qredf post-loop
  __shared__ float elds[128];
  __shared__ float esl[128];

  const int tid = threadIdx.x;
  const int l = tid & 63;
  const int w = tid >> 6;  // wave 0..7 = j-tile
  const int g = blockIdx.x;

  const int n0 = segstart[g];
  const int n1 = segstart[g + 1];
  const int cnt = n1 - n0;
  if (cnt <= 0) return;  // block-uniform, before any barrier

  const int ntiles = (cnt + 127) >> 7;
  const float4* x4 = (const float4*)x;

  // A-fragments for this wave's j-tile (jt = w): registers, once per block
  short8 afrag[8];
#pragma unroll
  for (int kt = 0; kt < 8; ++kt) afrag[kt] = w1a[(kt * 8 + w) * 64 + l];

  // per-lane b1/W2 for j = 16*w + (l>>4)*4 + r
  const int j0 = 16 * w + (l >> 4) * 4;
  const float4 bb = *reinterpret_cast<const float4*>(b1 + j0);
  const float4 ww = *reinterpret_cast<const float4*>(W2 + j0);

  const int lanecol = l & 31;  // float4 index within a half-row
  const int rhalf = l >> 5;    // 0/1: which row of the pair

  // sweep mapping
  const int c2 = tid & 127;
  const int qh = tid >> 7;
  float2 pacc = make_float2(0.f, 0.f);
  float es_acc = 0.f;  // valid for tid<128

  char* xl = (char*)xlds8;
  float4 rrA[8], rrB[8];  // never simultaneously live past the MFMA phase
  uint2 curA[8];          // packed first channel-half

  // prologue: load + write tile 0 (rows beyond n1 read clamped real data;
  // their contributions are killed later by e=0)
#pragma unroll
  for (int i = 0; i < 8; ++i) {
    const int node = min(n0 + w * 16 + 2 * i + rhalf, N - 1);
    rrA[i] = x4[(size_t)node * 64 + lanecol];
  }
#pragma unroll
  for (int i = 0; i < 8; ++i) curA[i] = pack4(rrA[i]);
#pragma unroll
  for (int i = 0; i < 8; ++i) {
    const int node = min(n0 + w * 16 + 2 * i + rhalf, N - 1);
    rrB[i] = x4[(size_t)node * 64 + 32 + lanecol];
  }
#pragma unroll
  for (int i = 0; i < 8; ++i) {
    const int r = w * 16 + 2 * i + rhalf;
    const int swz = (r & 7) << 4;
    *reinterpret_cast<uint2*>(xl + r * 512 + ((lanecol * 8) ^ swz)) = curA[i];
    *reinterpret_cast<uint2*>(xl + r * 512 + ((256 + lanecol * 8) ^ swz)) =
        pack4(rrB[i]);
  }
  __syncthreads();  // B1: tile 0 visible

  for (int t = 0; t < ntiles; ++t) {
    const bool more = (t + 1) < ntiles;

    // issue next tile's first channel-half (hides under MFMA phase)
    if (more) {
#pragma unroll
      for (int i = 0; i < 8; ++i) {
        const int node =
            min(n0 + (t + 1) * 128 + w * 16 + 2 * i + rhalf, N - 1);
        rrA[i] = x4[(size_t)node * 64 + lanecol];
      }
      __builtin_amdgcn_sched_barrier(0);
    }

    // ---- gate GEMM: wave w computes h[16w..16w+16][all 128 nodes] --------
#pragma unroll
    for (int nt = 0; nt < 8; ++nt) {
      const int ntw = (nt + w) & 7;  // decorrelate waves' LDS banks
      const int node = ntw * 16 + (l & 15);
      const int nb = node * 512;
      const int swz = (node & 7) << 4;
      f32x4 acc = (f32x4)(0.f);
#pragma unroll
      for (int kh = 0; kh < 2; ++kh) {
        short8 bfrag[4];
#pragma unroll
        for (int kk = 0; kk < 4; ++kk) {
          const int kt = kh * 4 + kk;
          bfrag[kk] = *reinterpret_cast<const short8*>(
              xl + nb + ((kt * 64 + ((l >> 4) << 4)) ^ swz));
        }
#pragma unroll
        for (int kk = 0; kk < 4; ++kk) {
          acc = __builtin_amdgcn_mfma_f32_16x16x32_bf16(afrag[kh * 4 + kk],
                                                        bfrag[kk], acc, 0, 0, 0);
        }
      }
      // epilogue: partial s over this wave's 16 j's for this node
      float t0 = __expf(2.f * (acc[0] + bb.x));
      float t1 = __expf(2.f * (acc[1] + bb.y));
      float t2 = __expf(2.f * (acc[2] + bb.z));
      float t3 = __expf(2.f * (acc[3] + bb.w));
      float ps = (1.f - 2.f / (t0 + 1.f)) * ww.x +
                 (1.f - 2.f / (t1 + 1.f)) * ww.y +
                 (1.f - 2.f / (t2 + 1.f)) * ww.z +
                 (1.f - 2.f / (t3 + 1.f)) * ww.w;
      ps += __shfl_xor(ps, 16, 64);
      ps += __shfl_xor(ps, 32, 64);
      if (l < 16) spart[w * 128 + ntw * 16 + l] = ps;
    }
    __syncthreads();  // B2: spart ready

    // pack first half (rrA landed during MFMA phase; rrA dies here),
    // then issue second channel-half (hides under combine + sweep)
    if (more) {
#pragma unroll
      for (int i = 0; i < 8; ++i) curA[i] = pack4(rrA[i]);
#pragma unroll
      for (int i = 0; i < 8; ++i) {
        const int node =
            min(n0 + (t + 1) * 128 + w * 16 + 2 * i + rhalf, N - 1);
        rrB[i] = x4[(size_t)node * 64 + 32 + lanecol];
      }
      __builtin_amdgcn_sched_barrier(0);
    }

    // combine j-slices -> s -> e (one thread per node)
    if (tid < 128) {
      float s = 0.f;
#pragma unroll
      for (int wv = 0; wv < 8; ++wv) s += spart[wv * 128 + tid];
      const int node = n0 + t * 128 + tid;
      const float e = (node < n1) ? __expf(s) : 0.f;
      elds[tid] = e;
      es_acc += e;
    }
    __syncthreads();  // B3: elds ready

    // ---- channel-major pool sweep: channels {2c2,2c2+1}, nodes qh*32.. ----
#pragma unroll 8
    for (int m = 0; m < 32; ++m) {
      const int n = qh * 32 + m;
      const unsigned v = *reinterpret_cast<const unsigned*>(
          xl + n * 512 + ((c2 * 4) ^ ((n & 7) << 4)));
      const float ee = elds[n];
      const float xlo = __builtin_bit_cast(float, v << 16);
      const float xhi = __builtin_bit_cast(float, v & 0xFFFF0000u);
      pacc.x = fmaf(xlo, ee, pacc.x);
      pacc.y = fmaf(xhi, ee, pacc.y);
    }
    __syncthreads();  // B4: all reads of tile t done

    // write tile t+1 (curA packed; rrB packed here, loads landed under sweep)
    if (more) {
#pragma unroll
      for (int i = 0; i < 8; ++i) {
        const int r = w * 16 + 2 * i + rhalf;
        const int swz = (r & 7) << 4;
        *reinterpret_cast<uint2*>(xl + r * 512 + ((lanecol * 8) ^ swz)) =
            curA[i];
        *reinterpret_cast<uint2*>(xl + r * 512 + ((256 + lanecol * 8) ^ swz)) =
            pack4(rrB[i]);
      }
      __syncthreads();  // B1': tile t+1 visible
    }
  }

  // ---- combine quarter partials; spart reused as qredf [4][256] ----
  float* qredf = spart;
  qredf[qh * 256 + c2 * 2] = pacc.x;
  qredf[qh * 256 + c2 * 2 + 1] = pacc.y;
  if (tid < 128) esl[tid] = es_acc;
  __syncthreads();
  if (tid < 64) esl[tid] += esl[tid + 64];
  __syncthreads();

  float* er = (float*)xlds8;  // x-tile dead: reuse for emb/proj buffers
  if (tid < HH) {
    float es = 0.f;
#pragma unroll 8
    for (int i = 0; i < 64; ++i) es += esl[i];
    const float inv = (es > 0.f) ? 1.f / es : 0.f;
    const float emb =
        qredf[tid] + qredf[256 + tid] + qredf[512 + tid] + qredf[768 + tid];
    er[tid] = emb * inv;
  }
  __syncthreads();

  // projection: ctx = er @ Wp + bp, split over k-halves
  float* pr = er + 256;  // [2][256]
  {
    const int c = tid & 255;
    const int h = tid >> 8;
    float p = 0.f;
    const float* wp = Wp + (size_t)h * 128 * HH + c;
#pragma unroll 4
    for (int k = 0; k < 128; ++k) {
      p = fmaf(er[h * 128 + k], wp[(size_t)k * HH], p);
    }
    pr[h * 256 + c] = p;
  }
  __syncthreads();
  float* ctxl = pr + 512;
  if (tid < HH) {
    ctxl[tid] = pr[tid] + pr[256 + tid] + bp[tid];
  }
  __syncthreads();

  // broadcast ctx row to all nodes of the graph (coalesced 1KB/wave rows)
  {
    const int q = tid & 63;
    const float4 cv = reinterpret_cast<const float4*>(ctxl)[q];
    for (int n = n0 + w; n < n1; n += 8) {
      out4[(size_t)n * 64 + q] = cv;
    }
  }
}

extern "C" void kernel_launch(void* const* d_in, const int* in_sizes, int n_in,
                              void* d_out, int out_size, void* d_ws, size_t ws_size,
                              hipStream_t stream) {
  const float* x = (const float*)d_in[0];
  const int* batch = (const int*)d_in[1];
  const float* W1 = (const float*)d_in[2];
  const float* b1 = (const float*)d_in[3];
  const float* W2 = (const float*)d_in[4];
  // d_in[5] = b2 (unused: softmax shift-invariant)
  const float* Wp = (const float*)d_in[6];
  const float* bp = (const float*)d_in[7];
  float* out = (float*)d_out;

  const int N = in_sizes[1];
  const int G = GG;

  // workspace layout (16B aligned)
  char* wsp = (char*)d_ws;
  short8* w1a = (short8*)wsp;           // 4096 short8 = 64 KB
  size_t off = 4096 * sizeof(short8);
  int* segstart = (int*)(wsp + off);    // G+1 ints

  // fragment W1
  w1frag_kernel<<<dim3(64), 64, 0, stream>>>(W1, w1a);
  // segment offsets
  {
    dim3 grid((N + 255) / 256);
    segstart_kernel<<<grid, 256, 0, stream>>>(batch, segstart, N, G);
  }
  // fused gate + pool + project + broadcast
  fused_kernel<<<dim3(G), 512, 0, stream>>>(x, w1a, b1, W2, segstart, Wp, bp,
                                            (float4*)out, N);
}

// Round 13
// 116.939 us; speedup vs baseline: 2.4378x; 1.0851x over previous
//
#include <hip/hip_runtime.h>
#include <hip/hip_bf16.h>

#define HH 256   // hidden dim
#define HJ 128   // H/2
#define GG 512   // number of graphs

typedef __attribute__((ext_vector_type(8))) short short8;
typedef __attribute__((ext_vector_type(4))) float f32x4;

static __device__ __forceinline__ unsigned f2bfu(float f) {
  // round-to-nearest-even fp32 -> bf16 (inputs finite), as low 16 bits
  unsigned u = __builtin_bit_cast(unsigned, f);
  return (u + 0x7FFFu + ((u >> 16) & 1u)) >> 16;
}

static __device__ __forceinline__ uint2 pack4(const float4 f) {
  return make_uint2(f2bfu(f.x) | (f2bfu(f.y) << 16),
                    f2bfu(f.z) | (f2bfu(f.w) << 16));
}

// ---------------- Kernel 0: pre-fragment W1^T into MFMA A-operand order ----
// w1a[kt*8+jt][lane] = 8 bf16: A[m=j][k] with j = jt*16+(l&15), k = kt*32+(l>>4)*8+i
__global__ __launch_bounds__(64) void w1frag_kernel(
    const float* __restrict__ W1, short8* __restrict__ w1a) {
  const int l = threadIdx.x;
  const int kt = blockIdx.x >> 3;
  const int jt = blockIdx.x & 7;
  const int j = jt * 16 + (l & 15);
  const int kb = kt * 32 + (l >> 4) * 8;
  short8 v;
#pragma unroll
  for (int i = 0; i < 8; ++i) v[i] = (short)f2bfu(W1[(size_t)(kb + i) * HJ + j]);
  w1a[blockIdx.x * 64 + l] = v;
}

// ---------------- segment offsets from sorted batch ----------------
__global__ __launch_bounds__(256) void segstart_kernel(
    const int* __restrict__ batch, int* __restrict__ segstart, int N, int G) {
  const int n = blockIdx.x * 256 + threadIdx.x;
  if (n >= N) return;
  const int b = batch[n];
  const int p = (n == 0) ? -1 : batch[n - 1];
  for (int g = p + 1; g <= b; ++g) segstart[g] = n;
  if (n == N - 1) {
    for (int g = b + 1; g <= G; ++g) segstart[g] = N;
  }
}

// ---------------- Fused kernel: one block per graph, wave-specialized ------
// Waves 0-3 (gate): MFMA tile i + tanh epilogue -> spart[i&1].
// Waves 4-7 (pool): combine e(i-1), sweep tile i-1, stage tile i+1.
// 3 LDS tile buffers (64 nodes x 256 ch bf16, XOR-swizzled); 1 barrier/iter.
__global__ __launch_bounds__(512) void fused_kernel(
    const float* __restrict__ x, const short8* __restrict__ w1a,
    const float* __restrict__ b1, const float* __restrict__ W2,
    const int* __restrict__ segstart, const float* __restrict__ Wp,
    const float* __restrict__ bp, float4* __restrict__ out4, int N) {
  __shared__ char xb[3 * 32768];     // 96 KB: 3 bf16 x-tiles [64][256] swizzled
  __shared__ float spart[2][8][64];  // 4 KB: per-j-tile partial s, dbuf
  __shared__ float elds[64];
  __shared__ float esums;

  const int tid = threadIdx.x;
  const int l = tid & 63;
  const int w = tid >> 6;  // wave 0..7
  const int g = blockIdx.x;

  const int n0 = segstart[g];
  const int n1 = segstart[g + 1];
  const int cnt = n1 - n0;
  if (cnt <= 0) return;  // block-uniform, before any barrier

  const int ntiles = (cnt + 63) >> 6;
  const float4* x4 = (const float4*)x;

  // gate waves: A-frags + b1/W2 for j-tiles jt0 and jt0+4
  const int jt0 = w & 3;
  short8 afrag[2][8];
  float4 bb[2], ww[2];
  if (w < 4) {
#pragma unroll
    for (int jj = 0; jj < 2; ++jj) {
      const int jt = jt0 + jj * 4;
#pragma unroll
      for (int kt = 0; kt < 8; ++kt) afrag[jj][kt] = w1a[(kt * 8 + jt) * 64 + l];
      const int j0 = 16 * jt + (l >> 4) * 4;
      bb[jj] = *reinterpret_cast<const float4*>(b1 + j0);
      ww[jj] = *reinterpret_cast<const float4*>(W2 + j0);
    }
  }

  // prologue: all 8 waves stage tile 0 (wave w: rows w*8..w*8+7, 1KB bursts)
  {
    float4 rr[8];
#pragma unroll
    for (int k = 0; k < 8; ++k) {
      const int node = min(n0 + w * 8 + k, N - 1);
      rr[k] = x4[(size_t)node * 64 + l];
    }
#pragma unroll
    for (int k = 0; k < 8; ++k) {
      const int r = w * 8 + k;
      const int swz = (r & 7) << 4;
      *reinterpret_cast<uint2*>(xb + r * 512 + ((l * 8) ^ swz)) = pack4(rr[k]);
    }
  }
  __syncthreads();

  const int c2 = tid & 127;        // pool sweep: channel pair
  const int qh = (tid >> 7) & 1;   // pool sweep: node half
  float2 pacc = make_float2(0.f, 0.f);
  float es_acc = 0.f;

  for (int i = 0; i < ntiles; ++i) {
    if (w < 4) {
      // ---- gate: MFMA tile i -> spart[i&1] ----
      const char* xbi = xb + (i % 3) * 32768;
      float* sp = &spart[i & 1][0][0];
#pragma unroll
      for (int nt = 0; nt < 4; ++nt) {
        const int node = nt * 16 + (l & 15);
        const int nb = node * 512;
        const int swz = (node & 7) << 4;
        short8 bfrag[8];
#pragma unroll
        for (int kt = 0; kt < 8; ++kt) {
          bfrag[kt] = *reinterpret_cast<const short8*>(
              xbi + nb + ((kt * 64 + ((l >> 4) << 4)) ^ swz));
        }
#pragma unroll
        for (int jj = 0; jj < 2; ++jj) {
          f32x4 acc = (f32x4)(0.f);
#pragma unroll
          for (int kt = 0; kt < 8; ++kt) {
            acc = __builtin_amdgcn_mfma_f32_16x16x32_bf16(afrag[jj][kt],
                                                          bfrag[kt], acc, 0, 0, 0);
          }
          float t0 = __expf(2.f * (acc[0] + bb[jj].x));
          float t1 = __expf(2.f * (acc[1] + bb[jj].y));
          float t2 = __expf(2.f * (acc[2] + bb[jj].z));
          float t3 = __expf(2.f * (acc[3] + bb[jj].w));
          float ps = (1.f - 2.f / (t0 + 1.f)) * ww[jj].x +
                     (1.f - 2.f / (t1 + 1.f)) * ww[jj].y +
                     (1.f - 2.f / (t2 + 1.f)) * ww[jj].z +
                     (1.f - 2.f / (t3 + 1.f)) * ww[jj].w;
          ps += __shfl_xor(ps, 16, 64);
          ps += __shfl_xor(ps, 32, 64);
          if (l < 16) sp[(jt0 + jj * 4) * 64 + node] = ps;
        }
      }
    } else {
      // ---- pool: combine e(i-1) + sweep tile i-1, then stage tile i+1 ----
      if (i >= 1) {
        const float* sp = &spart[(i - 1) & 1][0][0];
        float s = 0.f;
#pragma unroll
        for (int jt = 0; jt < 8; ++jt) s += sp[jt * 64 + l];
        const int node = n0 + (i - 1) * 64 + l;
        const float e = (node < n1) ? __expf(s) : 0.f;
        elds[l] = e;  // all 4 pool waves write identical values
        if (w == 4) es_acc += e;
        const char* xbs = xb + ((i - 1) % 3) * 32768;
#pragma unroll 8
        for (int m = 0; m < 32; ++m) {
          const int n = qh * 32 + m;
          const unsigned v = *reinterpret_cast<const unsigned*>(
              xbs + n * 512 + ((c2 * 4) ^ ((n & 7) << 4)));
          const float ee = elds[n];
          pacc.x = fmaf(__builtin_bit_cast(float, v << 16), ee, pacc.x);
          pacc.y = fmaf(__builtin_bit_cast(float, v & 0xFFFF0000u), ee, pacc.y);
        }
      }
      if (i + 1 < ntiles) {
        char* xbd = xb + ((i + 1) % 3) * 32768;
        const int rb = (w - 4) * 16;
        float4 rr[8];
#pragma unroll
        for (int b = 0; b < 2; ++b) {
#pragma unroll
          for (int k = 0; k < 8; ++k) {
            const int node = min(n0 + (i + 1) * 64 + rb + b * 8 + k, N - 1);
            rr[k] = x4[(size_t)node * 64 + l];
          }
#pragma unroll
          for (int k = 0; k < 8; ++k) {
            const int r = rb + b * 8 + k;
            const int swz = (r & 7) << 4;
            *reinterpret_cast<uint2*>(xbd + r * 512 + ((l * 8) ^ swz)) =
                pack4(rr[k]);
          }
        }
      }
    }
    __syncthreads();
  }

  // drain: combine + sweep the last tile (pool waves)
  if (w >= 4) {
    const float* sp = &spart[(ntiles - 1) & 1][0][0];
    float s = 0.f;
#pragma unroll
    for (int jt = 0; jt < 8; ++jt) s += sp[jt * 64 + l];
    const int node = n0 + (ntiles - 1) * 64 + l;
    const float e = (node < n1) ? __expf(s) : 0.f;
    elds[l] = e;
    if (w == 4) es_acc += e;
    const char* xbs = xb + ((ntiles - 1) % 3) * 32768;
#pragma unroll 8
    for (int m = 0; m < 32; ++m) {
      const int n = qh * 32 + m;
      const unsigned v = *reinterpret_cast<const unsigned*>(
          xbs + n * 512 + ((c2 * 4) ^ ((n & 7) << 4)));
      const float ee = elds[n];
      pacc.x = fmaf(__builtin_bit_cast(float, v << 16), ee, pacc.x);
      pacc.y = fmaf(__builtin_bit_cast(float, v & 0xFFFF0000u), ee, pacc.y);
    }
    if (w == 4) {
      float es = es_acc;
      es += __shfl_xor(es, 1, 64);
      es += __shfl_xor(es, 2, 64);
      es += __shfl_xor(es, 4, 64);
      es += __shfl_xor(es, 8, 64);
      es += __shfl_xor(es, 16, 64);
      es += __shfl_xor(es, 32, 64);
      if (l == 0) esums = es;
    }
  }
  __syncthreads();

  // ---- pooled partials -> emb -> proj -> broadcast (xb reused as float) ----
  float* fbase = (float*)xb;  // qredf [2][256] at 0; er at +512; pr at +768
  if (w >= 4) {
    fbase[qh * 256 + c2 * 2] = pacc.x;
    fbase[qh * 256 + c2 * 2 + 1] = pacc.y;
  }
  __syncthreads();

  float* er = fbase + 512;
  if (tid < HH) {
    const float es = esums;
    const float inv = (es > 0.f) ? 1.f / es : 0.f;
    er[tid] = (fbase[tid] + fbase[256 + tid]) * inv;
  }
  __syncthreads();

  float* pr = fbase + 768;
  {
    const int c = tid & 255;
    const int h2 = tid >> 8;
    float p = 0.f;
    const float* wp = Wp + (size_t)h2 * 128 * HH + c;
#pragma unroll 4
    for (int k = 0; k < 128; ++k) {
      p = fmaf(er[h2 * 128 + k], wp[(size_t)k * HH], p);
    }
    pr[h2 * 256 + c] = p;
  }
  __syncthreads();
  float* ctxl = fbase + 1280;
  if (tid < HH) {
    ctxl[tid] = pr[tid] + pr[256 + tid] + bp[tid];
  }
  __syncthreads();

  // broadcast ctx row to all nodes of the graph (coalesced 1KB/wave rows)
  {
    const int q = tid & 63;
    const float4 cv = reinterpret_cast<const float4*>(ctxl)[q];
    for (int n = n0 + w; n < n1; n += 8) {
      out4[(size_t)n * 64 + q] = cv;
    }
  }
}

extern "C" void kernel_launch(void* const* d_in, const int* in_sizes, int n_in,
                              void* d_out, int out_size, void* d_ws, size_t ws_size,
                              hipStream_t stream) {
  const float* x = (const float*)d_in[0];
  const int* batch = (const int*)d_in[1];
  const float* W1 = (const float*)d_in[2];
  const float* b1 = (const float*)d_in[3];
  const float* W2 = (const float*)d_in[4];
  // d_in[5] = b2 (unused: softmax shift-invariant)
  const float* Wp = (const float*)d_in[6];
  const float* bp = (const float*)d_in[7];
  float* out = (float*)d_out;

  const int N = in_sizes[1];
  const int G = GG;

  // workspace layout (16B aligned)
  char* wsp = (char*)d_ws;
  short8* w1a = (short8*)wsp;           // 4096 short8 = 64 KB
  size_t off = 4096 * sizeof(short8);
  int* segstart = (int*)(wsp + off);    // G+1 ints

  // fragment W1
  w1frag_kernel<<<dim3(64), 64, 0, stream>>>(W1, w1a);
  // segment offsets
  {
    dim3 grid((N + 255) / 256);
    segstart_kernel<<<grid, 256, 0, stream>>>(batch, segstart, N, G);
  }
  // fused gate + pool + project + broadcast (wave-specialized)
  fused_kernel<<<dim3(G), 512, 0, stream>>>(x, w1a, b1, W2, segstart, Wp, bp,
                                            (float4*)out, N);
}